// Round 11
// baseline (256.866 us; speedup 1.0000x reference)
//
#include <hip/hip_runtime.h>
#include <math.h>

#define BB 8
#define NN 4096
#define CC 128
#define SS 8
#define HH 64
#define HW 4096              // 64*64
#define PLANE_B (HW*CC)      // floats per (plane,batch) in transposed layout
#define SQRT_C 11.3137084989847603904f

// -------- transpose planes [B,C,H,W] -> [plane,B,HW,C] -----------------------
__global__ __launch_bounds__(128) void transpose_planes(
    const float* __restrict__ pxz, const float* __restrict__ pxy,
    const float* __restrict__ pyz, float* __restrict__ dst) {
  int bid = blockIdx.x;
  int c   = threadIdx.x;
  int hw0 = (bid & 255) * 16;
  int b   = (bid >> 8) & 7;
  int p   = bid >> 11;
  const float* src = (p == 0) ? pxz : (p == 1) ? pxy : pyz;
  const float4* s4 = (const float4*)(src + (size_t)(b * CC + c) * HW + hw0);
  float4 v0 = s4[0], v1 = s4[1], v2 = s4[2], v3 = s4[3];
  float vals[16];
  vals[0]=v0.x; vals[1]=v0.y; vals[2]=v0.z; vals[3]=v0.w;
  vals[4]=v1.x; vals[5]=v1.y; vals[6]=v1.z; vals[7]=v1.w;
  vals[8]=v2.x; vals[9]=v2.y; vals[10]=v2.z; vals[11]=v2.w;
  vals[12]=v3.x; vals[13]=v3.y; vals[14]=v3.z; vals[15]=v3.w;
  float* d = dst + (size_t)(p * BB + b) * PLANE_B + (size_t)hw0 * CC + c;
#pragma unroll
  for (int i = 0; i < 16; ++i) d[i * CC] = vals[i];
}

// ------------- per-batch spatial clustering: counting sort by Morton cell ----
__device__ __forceinline__ int morton3_3(int cx, int cy, int cz) {
  int m = 0;
#pragma unroll
  for (int k = 0; k < 3; ++k) {
    m |= ((cx >> k) & 1) << (3 * k);
    m |= ((cy >> k) & 1) << (3 * k + 1);
    m |= ((cz >> k) & 1) << (3 * k + 2);
  }
  return m;
}

__global__ __launch_bounds__(1024) void sort_queries(
    const float* __restrict__ qpos, int* __restrict__ sidx) {
  const int b = blockIdx.x;
  const int t = threadIdx.x;
  __shared__ unsigned short scell[NN];
  __shared__ int hist[512];
  __shared__ int tmp[512];
  __shared__ int cur[512];
  if (t < 512) hist[t] = 0;
  __syncthreads();
  for (int i = t; i < NN; i += 1024) {
    const float* qp = qpos + ((size_t)b * NN + i) * 3;
    float x = qp[0], y = qp[1], z = qp[2];
    int cx = min(7, max(0, (int)((x + 1.f) * 4.f)));
    int cy = min(7, max(0, (int)((y + 1.f) * 4.f)));
    int cz = min(7, max(0, (int)((z + 1.f) * 4.f)));
    int cell = morton3_3(cx, cy, cz);
    scell[i] = (unsigned short)cell;
    atomicAdd(&hist[cell], 1);
  }
  __syncthreads();
  if (t < 512) tmp[t] = hist[t];
  __syncthreads();
  for (int off = 1; off < 512; off <<= 1) {
    int v = 0;
    if (t < 512 && t >= off) v = tmp[t - off];
    __syncthreads();
    if (t < 512) tmp[t] += v;
    __syncthreads();
  }
  if (t < 512) cur[t] = tmp[t] - hist[t];
  __syncthreads();
  for (int i = t; i < NN; i += 1024) {
    int cell = scell[i];
    int pos = atomicAdd(&cur[cell], 1);
    sidx[b * NN + pos] = i;
  }
}

// ---------------- precompute fused matrices (TRANSPOSED for row reads) -------
// MtT[c][cp] = sqrt(C) * sum_d Wk[c,d]*Wq[cp,d]   (qk_c = u_c + sum_cp MtT[c][cp]*feat_cp)
// u[c]      = sqrt(C) * sum_d Wk[c,d]*bq[d]
// W2T[d][cp] = sum_e Wv[cp,e]*Wout[e,d]           (o_d = b2_d + sum_cp W2T[d][cp]*w_cp)
// b2[d]     = sum_e bv[e]*Wout[e,d] + bout[d]
// Wofft[j][c] = Woff[c][j]
__global__ __launch_bounds__(128) void prep_mats(
    const float* __restrict__ Wq, const float* __restrict__ bq,
    const float* __restrict__ Wk,
    const float* __restrict__ Wv, const float* __restrict__ bv,
    const float* __restrict__ Wout, const float* __restrict__ bout,
    const float* __restrict__ Woff,
    float* __restrict__ MtT, float* __restrict__ u,
    float* __restrict__ W2T, float* __restrict__ b2,
    float* __restrict__ Wofft) {
  int t = threadIdx.x;
  int blk = blockIdx.x;
  if (blk < 128) {                 // cp = blk, thread = c
    __shared__ float lwq[128];
    lwq[t] = Wq[blk * 128 + t];
    __syncthreads();
    float acc = 0.f;
#pragma unroll 8
    for (int d = 0; d < 128; ++d) acc += Wk[t * 128 + d] * lwq[d];
    MtT[t * 128 + blk] = SQRT_C * acc;
  } else if (blk < 256) {          // cp = blk-128, thread = d
    int cp = blk - 128;
    float acc = 0.f;
#pragma unroll 8
    for (int e = 0; e < 128; ++e) acc += Wv[cp * 128 + e] * Wout[e * 128 + t];
    W2T[t * 128 + cp] = acc;
  } else if (blk == 256) {         // u and b2
    float au = 0.f, ab = 0.f;
    for (int d = 0; d < 128; ++d) au += Wk[t * 128 + d] * bq[d];
    u[t] = SQRT_C * au;
    for (int e = 0; e < 128; ++e) ab += bv[e] * Wout[e * 128 + t];
    b2[t] = ab + bout[t];
  } else {                         // Woff transpose
#pragma unroll
    for (int j = 0; j < 24; ++j) Wofft[j * 128 + t] = Woff[t * 24 + j];
  }
}

// ---------------- bilinear combo: 4 byte-offsets + 4 corner weights ----------
__device__ __forceinline__ void make_combo(float cx, float cy,
                                           int4* oi, float4* ow) {
  float fx = fminf(fmaxf((cx + 1.f) * 31.5f, 0.f), 63.f);
  float fy = fminf(fmaxf((cy + 1.f) * 31.5f, 0.f), 63.f);
  float x0f = floorf(fx), y0f = floorf(fy);
  int x0 = (int)x0f, y0 = (int)y0f;
  int x1 = min(x0 + 1, 63), y1 = min(y0 + 1, 63);
  float wx = fx - x0f, wy = fy - y0f;
  int r0 = y0 << 15, r1 = y1 << 15;     // hw-row stride = 64*128*4 B
  int cb0 = x0 << 9, cb1 = x1 << 9;     // hw-col stride = 128*4 B
  *oi = make_int4(r0 + cb0, r0 + cb1, r1 + cb0, r1 + cb1);
  float wxy = wx * wy;
  *ow = make_float4(1.f - wx - wy + wxy, wx - wxy, wy - wxy, wxy);
}

__device__ __forceinline__ float2 ld2(const char* p, int off) {
  return *(const float2*)(p + off);
}

// ---------------- main fused kernel v11 -------------------------------------
// Phases A/C: lane l owns channels (2l,2l+1); wave owns 4 queries.
// Phase C is fully wave-local (complete butterfly in-wave, softmax via
// shuffles, ZERO barriers) with corner RELOAD for the weighted pass instead
// of retaining sample arrays (anti-spill). Phases B/B2/F: thread = channel,
// transposed weight rows read as float4. Queries Morton-sorted via sidx.
__global__ __launch_bounds__(128, 4) void deform_attn11(
    const float* __restrict__ qpos, const int* __restrict__ sidx,
    const float* __restrict__ pT,
    const float* __restrict__ MtT, const float* __restrict__ u,
    const float* __restrict__ W2T, const float* __restrict__ bias2,
    const float* __restrict__ Wofft, const float* __restrict__ boff,
    float* __restrict__ out) {
  const int tid = threadIdx.x;
  const int c = tid;
  const int l = tid & 63;
  const int wv = tid >> 6;
  const int qb = wv * 4;               // queries owned in phases A/C
  const int bid = blockIdx.x;
  const int b = bid & 7;               // batch -> XCD locality heuristic
  const int n0 = (bid >> 3) * 8;

  __shared__ int snidx[8];
  __shared__ float spos[24];
  __shared__ int4   sfi[24];           // feature combos [p][q]
  __shared__ float4 sfw[24];
  __shared__ int4   sci[192];          // aux combos [p][q][j] = p*64+q*8+j
  __shared__ float4 scw[192];
  __shared__ __align__(16) float sbuf[CC * 8];    // features (live through F)
  __shared__ __align__(16) float swacc[CC * 8];   // qk, then w
  __shared__ float soff[8][24];

  if (tid < 8) snidx[tid] = sidx[b * NN + n0 + tid];
  __syncthreads();
  if (tid < 24) {
    int q = tid / 3, comp = tid - q * 3;
    spos[tid] = qpos[((size_t)b * NN + snidx[q]) * 3 + comp];
  }
  __syncthreads();

  // gather bases: channel pair (2l,2l+1) -> +8l bytes
  const char* gp0 = (const char*)(pT + (size_t)(0 * BB + b) * PLANE_B) + 8 * l;
  const char* gp1 = (const char*)(pT + (size_t)(1 * BB + b) * PLANE_B) + 8 * l;
  const char* gp2 = (const char*)(pT + (size_t)(2 * BB + b) * PLANE_B) + 8 * l;

  // ---- feature combos (24 = 3 planes x 8 queries) ----
  if (tid < 24) {
    int p = tid >> 3, q = tid & 7;
    float px = spos[q * 3 + 0], py = spos[q * 3 + 1], pz = spos[q * 3 + 2];
    float cx = (p == 2) ? py : px;
    float cy = (p == 1) ? py : pz;
    make_combo(cx, cy, &sfi[tid], &sfw[tid]);
  }
  __syncthreads();

  // ---- Phase A: feature sampling (2 ch/lane, 4 queries/wave, float2) ----
  {
    float f0q[4], f1q[4];
#pragma unroll
    for (int qi = 0; qi < 4; ++qi) {
      int q = qb + qi;
      float f0 = 0.f, f1 = 0.f;
#pragma unroll
      for (int p = 0; p < 3; ++p) {
        const char* g = (p == 0) ? gp0 : (p == 1) ? gp1 : gp2;
        int4 oi = sfi[p * 8 + q];
        float4 w = sfw[p * 8 + q];
        float2 v;
        v = ld2(g, oi.x); f0 += w.x * v.x; f1 += w.x * v.y;
        v = ld2(g, oi.y); f0 += w.y * v.x; f1 += w.y * v.y;
        v = ld2(g, oi.z); f0 += w.z * v.x; f1 += w.z * v.y;
        v = ld2(g, oi.w); f0 += w.w * v.x; f1 += w.w * v.y;
      }
      f0q[qi] = f0; f1q[qi] = f1;
    }
    *(float4*)&sbuf[(2 * l) * 8 + qb]     = make_float4(f0q[0], f0q[1], f0q[2], f0q[3]);
    *(float4*)&sbuf[(2 * l + 1) * 8 + qb] = make_float4(f1q[0], f1q[1], f1q[2], f1q[3]);
  }
  __syncthreads();

  // ---- Phase B: qk matvec, MtT row c read as float4; qk -> swacc ----
  {
    float uc = u[c];
    float qk[8];
#pragma unroll
    for (int q = 0; q < 8; ++q) qk[q] = uc;
    const float4* mrow = (const float4*)(MtT + (size_t)c * 128);
#pragma unroll 4
    for (int cp4 = 0; cp4 < 32; ++cp4) {
      float4 m4 = mrow[cp4];
#pragma unroll
      for (int k = 0; k < 4; ++k) {
        int cp = cp4 * 4 + k;
        float mk = (k == 0) ? m4.x : (k == 1) ? m4.y : (k == 2) ? m4.z : m4.w;
        float4 f0 = *(const float4*)&sbuf[cp * 8];
        float4 f1 = *(const float4*)&sbuf[cp * 8 + 4];
        qk[0] += mk * f0.x; qk[1] += mk * f0.y; qk[2] += mk * f0.z; qk[3] += mk * f0.w;
        qk[4] += mk * f1.x; qk[5] += mk * f1.y; qk[6] += mk * f1.z; qk[7] += mk * f1.w;
      }
    }
    *(float4*)&swacc[c * 8]     = make_float4(qk[0], qk[1], qk[2], qk[3]);
    *(float4*)&swacc[c * 8 + 4] = make_float4(qk[4], qk[5], qk[6], qk[7]);
  }

  // ---- Phase B2: deformable offsets (192 dot products over 128 threads) ----
#pragma unroll
  for (int rep = 0; rep < 2; ++rep) {
    int m = rep * 128 + tid;
    if (m < 192) {
      int q = m / 24;
      int t24 = m - q * 24;
      float acc = boff[t24];
      const float* wrow = Wofft + t24 * 128;
#pragma unroll 4
      for (int cp = 0; cp < CC; ++cp) acc += sbuf[cp * 8 + q] * wrow[cp];
      soff[q][t24] = acc;
    }
  }
  __syncthreads();

  // ---- aux combos (192 = 3 planes x 8 q x 8 j) ----
#pragma unroll
  for (int rep = 0; rep < 2; ++rep) {
    int m = rep * 128 + tid;             // m = p*64 + q*8 + j
    if (m < 192) {
      int p = m >> 6, q = (m >> 3) & 7, j = m & 7;
      float ox = spos[q * 3 + 0] + soff[q][j * 3 + 0];
      float oy = spos[q * 3 + 1] + soff[q][j * 3 + 1];
      float oz = spos[q * 3 + 2] + soff[q][j * 3 + 2];
      float cx = (p == 2) ? oy : ox;
      float cy = (p == 1) ? oy : oz;
      make_combo(cx, cy, &sci[m], &scw[m]);
    }
  }
  __syncthreads();

  // ---- Phase C: wave-local (no barriers). Pass 1: logits; pass 2: reload ---
  {
    float4 q0v = *(const float4*)&swacc[(2 * l) * 8 + qb];
    float4 q1v = *(const float4*)&swacc[(2 * l + 1) * 8 + qb];
    const int lb0 = l & 1, lb1 = (l >> 1) & 1, lb2 = (l >> 2) & 1;
#pragma unroll
    for (int qi = 0; qi < 4; ++qi) {
      int q = qb + qi;
      float qv0 = (qi == 0) ? q0v.x : (qi == 1) ? q0v.y : (qi == 2) ? q0v.z : q0v.w;
      float qv1 = (qi == 0) ? q1v.x : (qi == 1) ? q1v.y : (qi == 2) ? q1v.z : q1v.w;
      // pass 1: partial logits (samples discarded)
      float part[8];
#pragma unroll
      for (int j = 0; j < 8; ++j) {
        float a0 = 0.f, a1 = 0.f;
#pragma unroll
        for (int p = 0; p < 3; ++p) {
          int idx = p * 64 + q * 8 + j;
          const char* g = (p == 0) ? gp0 : (p == 1) ? gp1 : gp2;
          int4 oi = sci[idx];
          float4 w = scw[idx];
          float2 v;
          v = ld2(g, oi.x); a0 += w.x * v.x; a1 += w.x * v.y;
          v = ld2(g, oi.y); a0 += w.y * v.x; a1 += w.y * v.y;
          v = ld2(g, oi.z); a0 += w.z * v.x; a1 += w.z * v.y;
          v = ld2(g, oi.w); a0 += w.w * v.x; a1 += w.w * v.y;
        }
        part[j] = a0 * qv0 + a1 * qv1;
      }
      // multi-value butterfly: complete 128-ch logits, lane ends with j = l&7
      float s2[4];
#pragma unroll
      for (int k = 0; k < 4; ++k) {
        float pa = part[2 * k], pb_ = part[2 * k + 1];
        float snd = lb0 ? pa : pb_;
        float kp  = lb0 ? pb_ : pa;
        s2[k] = kp + __shfl_xor(snd, 1);
      }
      float s4_[2];
#pragma unroll
      for (int k = 0; k < 2; ++k) {
        float pa = s2[2 * k], pb_ = s2[2 * k + 1];
        float snd = lb1 ? pa : pb_;
        float kp  = lb1 ? pb_ : pa;
        s4_[k] = kp + __shfl_xor(snd, 2);
      }
      float s8;
      {
        float snd = lb2 ? s4_[0] : s4_[1];
        float kp  = lb2 ? s4_[1] : s4_[0];
        s8 = kp + __shfl_xor(snd, 4);
      }
      s8 += __shfl_xor(s8, 8);
      s8 += __shfl_xor(s8, 16);
      s8 += __shfl_xor(s8, 32);
      // wave-local softmax over the 8 logits (each 8-lane group holds all 8)
      float mx = s8;
      mx = fmaxf(mx, __shfl_xor(mx, 1));
      mx = fmaxf(mx, __shfl_xor(mx, 2));
      mx = fmaxf(mx, __shfl_xor(mx, 4));
      float e = __expf(s8 - mx);
      float den = e;
      den += __shfl_xor(den, 1);
      den += __shfl_xor(den, 2);
      den += __shfl_xor(den, 4);
      float attn = e / den;              // lane's attn for j = l&7
      // pass 2: reload (L1/L2-hot) + attn-weighted accumulation
      float w0 = 0.f, w1 = 0.f;
#pragma unroll
      for (int j = 0; j < 8; ++j) {
        float aj = __shfl(attn, j);
        float a0 = 0.f, a1 = 0.f;
#pragma unroll
        for (int p = 0; p < 3; ++p) {
          int idx = p * 64 + q * 8 + j;
          const char* g = (p == 0) ? gp0 : (p == 1) ? gp1 : gp2;
          int4 oi = sci[idx];
          float4 w = scw[idx];
          float2 v;
          v = ld2(g, oi.x); a0 += w.x * v.x; a1 += w.x * v.y;
          v = ld2(g, oi.y); a0 += w.y * v.x; a1 += w.y * v.y;
          v = ld2(g, oi.z); a0 += w.z * v.x; a1 += w.z * v.y;
          v = ld2(g, oi.w); a0 += w.w * v.x; a1 += w.w * v.y;
        }
        w0 += aj * a0;
        w1 += aj * a1;
      }
      swacc[(2 * l) * 8 + q]     = w0;   // overwrite own qk slot
      swacc[(2 * l + 1) * 8 + q] = w1;
    }
  }
  __syncthreads();

  // ---- Phase F: o = w @ W2 + b2 + feature (thread = channel, W2T rows) ----
  {
    float bb = bias2[c];
    float o[8];
#pragma unroll
    for (int q = 0; q < 8; ++q) o[q] = bb;
    const float4* wrow = (const float4*)(W2T + (size_t)c * 128);
#pragma unroll 4
    for (int cp4 = 0; cp4 < 32; ++cp4) {
      float4 m4 = wrow[cp4];
#pragma unroll
      for (int k = 0; k < 4; ++k) {
        int cp = cp4 * 4 + k;
        float mk = (k == 0) ? m4.x : (k == 1) ? m4.y : (k == 2) ? m4.z : m4.w;
        float4 f0 = *(const float4*)&swacc[cp * 8];
        float4 f1 = *(const float4*)&swacc[cp * 8 + 4];
        o[0] += mk * f0.x; o[1] += mk * f0.y; o[2] += mk * f0.z; o[3] += mk * f0.w;
        o[4] += mk * f1.x; o[5] += mk * f1.y; o[6] += mk * f1.z; o[7] += mk * f1.w;
      }
    }
    float4 r0 = *(const float4*)&sbuf[c * 8];
    float4 r1 = *(const float4*)&sbuf[c * 8 + 4];
    out[((size_t)b * NN + snidx[0]) * CC + c] = o[0] + r0.x;
    out[((size_t)b * NN + snidx[1]) * CC + c] = o[1] + r0.y;
    out[((size_t)b * NN + snidx[2]) * CC + c] = o[2] + r0.z;
    out[((size_t)b * NN + snidx[3]) * CC + c] = o[3] + r0.w;
    out[((size_t)b * NN + snidx[4]) * CC + c] = o[4] + r1.x;
    out[((size_t)b * NN + snidx[5]) * CC + c] = o[5] + r1.y;
    out[((size_t)b * NN + snidx[6]) * CC + c] = o[6] + r1.z;
    out[((size_t)b * NN + snidx[7]) * CC + c] = o[7] + r1.w;
  }
}

// ---------------- last-resort fallback (no workspace) -----------------------
__device__ __forceinline__ float bil(const float* __restrict__ base,
                                     float cx, float cy, int es, int rs) {
  float fx = fminf(fmaxf((cx + 1.f) * 31.5f, 0.f), 63.f);
  float fy = fminf(fmaxf((cy + 1.f) * 31.5f, 0.f), 63.f);
  float x0f = floorf(fx), y0f = floorf(fy);
  int x0 = (int)x0f, y0 = (int)y0f;
  int x1 = min(x0 + 1, 63), y1 = min(y0 + 1, 63);
  float wx = fx - x0f, wy = fy - y0f;
  const float* r0 = base + y0 * rs;
  const float* r1 = base + y1 * rs;
  float f00 = r0[x0 * es], f01 = r0[x1 * es];
  float f10 = r1[x0 * es], f11 = r1[x1 * es];
  float top = f00 + (f01 - f00) * wx;
  float bot = f10 + (f11 - f10) * wx;
  return top + (bot - top) * wy;
}

__global__ __launch_bounds__(128) void deform_attn_fb(
    const float* __restrict__ qpos,
    const float* __restrict__ pxz, const float* __restrict__ pxy,
    const float* __restrict__ pyz,
    const float* __restrict__ MtT, const float* __restrict__ u,
    const float* __restrict__ W2T, const float* __restrict__ b2,
    const float* __restrict__ Woff, const float* __restrict__ boff,
    float* __restrict__ out) {
  const int tid = threadIdx.x;
  const int c = tid;
  const int bid = blockIdx.x;
  const int b = bid & 7;
  const int n0 = (bid >> 3) * 8;
  const int es = 1, rs = HH;
  const float* bxz = pxz + (size_t)(b * CC + c) * HW;
  const float* bxy = pxy + (size_t)(b * CC + c) * HW;
  const float* byz = pyz + (size_t)(b * CC + c) * HW;

  __shared__ __align__(16) float sfeat[CC * 8];
  __shared__ __align__(16) float swv[CC * 8];
  __shared__ float spos[24];
  __shared__ float soff[8][24];
  __shared__ float sred[8][2][8];

  if (tid < 24) spos[tid] = qpos[(size_t)(b * NN + n0) * 3 + tid];
  __syncthreads();
#pragma unroll
  for (int q = 0; q < 8; ++q) {
    float px = spos[q*3+0], py = spos[q*3+1], pz = spos[q*3+2];
    sfeat[c*8+q] = bil(bxz,px,pz,es,rs)+bil(bxy,px,py,es,rs)+bil(byz,py,pz,es,rs);
  }
  __syncthreads();
  float qk[8];
  {
    float uc = u[c];
#pragma unroll
    for (int q = 0; q < 8; ++q) qk[q] = uc;
    for (int cp = 0; cp < CC; ++cp) {
      float m = MtT[c*CC+cp];
#pragma unroll
      for (int q = 0; q < 8; ++q) qk[q] += m * sfeat[cp*8+q];
    }
  }
  if (tid < 120) {
    int q = tid/24, j = tid%24;
    float acc = boff[j];
    for (int cp = 0; cp < CC; ++cp) acc += sfeat[cp*8+q]*Woff[cp*24+j];
    soff[q][j] = acc;
  }
  if (tid < 72) {
    int q = 5+tid/24, j = tid%24;
    float acc = boff[j];
    for (int cp = 0; cp < CC; ++cp) acc += sfeat[cp*8+q]*Woff[cp*24+j];
    soff[q][j] = acc;
  }
  __syncthreads();
  const int wvid = tid >> 6;
  for (int q = 0; q < 8; ++q) {
    float px = spos[q*3+0], py = spos[q*3+1], pz = spos[q*3+2];
    float a8[8];
#pragma unroll
    for (int j = 0; j < 8; ++j) {
      float ox = px+soff[q][j*3+0], oy = py+soff[q][j*3+1], oz = pz+soff[q][j*3+2];
      float a = bil(bxz,ox,oz,es,rs)+bil(bxy,ox,oy,es,rs)+bil(byz,oy,oz,es,rs);
      a8[j] = a;
      float p = a * qk[q];
#pragma unroll
      for (int m = 1; m < 64; m <<= 1) p += __shfl_xor(p, m);
      if ((tid & 63) == 0) sred[q][wvid][j] = p;
    }
    __syncthreads();
    float attn[8], mx = -INFINITY;
#pragma unroll
    for (int j = 0; j < 8; ++j) { attn[j] = sred[q][0][j]+sred[q][1][j]; mx = fmaxf(mx, attn[j]); }
    float den = 0.f;
#pragma unroll
    for (int j = 0; j < 8; ++j) { attn[j] = __expf(attn[j]-mx); den += attn[j]; }
    float inv = 1.f/den, w = 0.f;
#pragma unroll
    for (int j = 0; j < 8; ++j) w += attn[j]*a8[j];
    swv[c*8+q] = w*inv;
  }
  __syncthreads();
  float o[8];
  {
    float bb = b2[c];
#pragma unroll
    for (int q = 0; q < 8; ++q) o[q] = bb;
    for (int cp = 0; cp < CC; ++cp) {
      float wv2 = W2T[c*CC+cp];
#pragma unroll
      for (int q = 0; q < 8; ++q) o[q] += wv2 * swv[cp*8+q];
    }
  }
#pragma unroll
  for (int q = 0; q < 8; ++q)
    out[(size_t)(b*NN+n0+q)*CC+c] = o[q] + sfeat[c*8+q];
}

extern "C" void kernel_launch(void* const* d_in, const int* in_sizes, int n_in,
                              void* d_out, int out_size, void* d_ws, size_t ws_size,
                              hipStream_t stream) {
  const float* qpos = (const float*)d_in[0];
  const float* pxz  = (const float*)d_in[1];
  const float* pxy  = (const float*)d_in[2];
  const float* pyz  = (const float*)d_in[3];
  const float* Wq   = (const float*)d_in[4];
  const float* bq   = (const float*)d_in[5];
  const float* Wk   = (const float*)d_in[6];
  // d_in[7] = bk: q.bk is constant over the S axis -> cancels in softmax
  const float* Wv   = (const float*)d_in[8];
  const float* bv   = (const float*)d_in[9];
  const float* Wout = (const float*)d_in[10];
  const float* bout = (const float*)d_in[11];
  const float* Woff = (const float*)d_in[12];
  const float* boff = (const float*)d_in[13];
  float* out = (float*)d_out;

  float* w = (float*)d_ws;
  const size_t nT = (size_t)3 * BB * HW * CC;
  const size_t matFloats = 16384 + 128 + 16384 + 128 + 24 * 128;
  const size_t sidxInts = (size_t)BB * NN;
  bool tp = ws_size >= (nT + matFloats + sidxInts) * sizeof(float);

  float* wsT  = w;
  float* wsMt = tp ? (w + nT) : w;
  float* wsU  = wsMt + 16384;
  float* wsW2 = wsU + 128;
  float* wsB2 = wsW2 + 16384;
  float* wsWofft = wsB2 + 128;
  int*   wsSidx  = (int*)(wsWofft + 24 * 128);

  prep_mats<<<258, 128, 0, stream>>>(Wq, bq, Wk, Wv, bv, Wout, bout, Woff,
                                     wsMt, wsU, wsW2, wsB2, wsWofft);
  if (tp) {
    sort_queries<<<BB, 1024, 0, stream>>>(qpos, wsSidx);
    transpose_planes<<<3 * BB * (HW / 16), 128, 0, stream>>>(pxz, pxy, pyz, wsT);
    deform_attn11<<<(BB * NN) / 8, 128, 0, stream>>>(
        qpos, wsSidx, wsT, wsMt, wsU, wsW2, wsB2, wsWofft, boff, out);
  } else {
    deform_attn_fb<<<(BB * NN) / 8, 128, 0, stream>>>(
        qpos, pxz, pxy, pyz, wsMt, wsU, wsW2, wsB2, Woff, boff, out);
  }
}

// Round 12
// 253.305 us; speedup vs baseline: 1.0141x; 1.0141x over previous
//
#include <hip/hip_runtime.h>
#include <math.h>

#define BB 8
#define NN 4096
#define CC 128
#define SS 8
#define HH 64
#define HW 4096              // 64*64
#define PLANE_B (HW*CC)      // floats per (plane,batch) in transposed layout
#define SQRT_C 11.3137084989847603904f

// -------- transpose planes [B,C,H,W] -> [plane,B,HW,C] -----------------------
__global__ __launch_bounds__(128) void transpose_planes(
    const float* __restrict__ pxz, const float* __restrict__ pxy,
    const float* __restrict__ pyz, float* __restrict__ dst) {
  int bid = blockIdx.x;
  int c   = threadIdx.x;
  int hw0 = (bid & 255) * 16;
  int b   = (bid >> 8) & 7;
  int p   = bid >> 11;
  const float* src = (p == 0) ? pxz : (p == 1) ? pxy : pyz;
  const float4* s4 = (const float4*)(src + (size_t)(b * CC + c) * HW + hw0);
  float4 v0 = s4[0], v1 = s4[1], v2 = s4[2], v3 = s4[3];
  float vals[16];
  vals[0]=v0.x; vals[1]=v0.y; vals[2]=v0.z; vals[3]=v0.w;
  vals[4]=v1.x; vals[5]=v1.y; vals[6]=v1.z; vals[7]=v1.w;
  vals[8]=v2.x; vals[9]=v2.y; vals[10]=v2.z; vals[11]=v2.w;
  vals[12]=v3.x; vals[13]=v3.y; vals[14]=v3.z; vals[15]=v3.w;
  float* d = dst + (size_t)(p * BB + b) * PLANE_B + (size_t)hw0 * CC + c;
#pragma unroll
  for (int i = 0; i < 16; ++i) d[i * CC] = vals[i];
}

// ------------- per-batch spatial clustering: counting sort by Morton cell ----
__device__ __forceinline__ int morton3_3(int cx, int cy, int cz) {
  int m = 0;
#pragma unroll
  for (int k = 0; k < 3; ++k) {
    m |= ((cx >> k) & 1) << (3 * k);
    m |= ((cy >> k) & 1) << (3 * k + 1);
    m |= ((cz >> k) & 1) << (3 * k + 2);
  }
  return m;
}

__global__ __launch_bounds__(1024) void sort_queries(
    const float* __restrict__ qpos, int* __restrict__ sidx) {
  const int b = blockIdx.x;
  const int t = threadIdx.x;
  __shared__ unsigned short scell[NN];
  __shared__ int hist[512];
  __shared__ int tmp[512];
  __shared__ int cur[512];
  if (t < 512) hist[t] = 0;
  __syncthreads();
  for (int i = t; i < NN; i += 1024) {
    const float* qp = qpos + ((size_t)b * NN + i) * 3;
    float x = qp[0], y = qp[1], z = qp[2];
    int cx = min(7, max(0, (int)((x + 1.f) * 4.f)));
    int cy = min(7, max(0, (int)((y + 1.f) * 4.f)));
    int cz = min(7, max(0, (int)((z + 1.f) * 4.f)));
    int cell = morton3_3(cx, cy, cz);
    scell[i] = (unsigned short)cell;
    atomicAdd(&hist[cell], 1);
  }
  __syncthreads();
  if (t < 512) tmp[t] = hist[t];
  __syncthreads();
  for (int off = 1; off < 512; off <<= 1) {
    int v = 0;
    if (t < 512 && t >= off) v = tmp[t - off];
    __syncthreads();
    if (t < 512) tmp[t] += v;
    __syncthreads();
  }
  if (t < 512) cur[t] = tmp[t] - hist[t];
  __syncthreads();
  for (int i = t; i < NN; i += 1024) {
    int cell = scell[i];
    int pos = atomicAdd(&cur[cell], 1);
    sidx[b * NN + pos] = i;
  }
}

// ---------------- precompute fused matrices (v9 layouts) ---------------------
// Mt[cp][c] = sqrt(C)*sum_d Wk[c,d]*Wq[cp,d];  u[c] = sqrt(C)*sum_d Wk[c,d]*bq[d]
// W2[cp][d] = sum_e Wv[cp,e]*Wout[e,d];        b2[d] = bv@Wout + bout
// Wofft[j][c] = Woff[c][j]
__global__ __launch_bounds__(128) void prep_mats(
    const float* __restrict__ Wq, const float* __restrict__ bq,
    const float* __restrict__ Wk,
    const float* __restrict__ Wv, const float* __restrict__ bv,
    const float* __restrict__ Wout, const float* __restrict__ bout,
    const float* __restrict__ Woff,
    float* __restrict__ Mt, float* __restrict__ u,
    float* __restrict__ W2, float* __restrict__ b2,
    float* __restrict__ Wofft) {
  int t = threadIdx.x;
  int blk = blockIdx.x;
  if (blk < 128) {
    __shared__ float lwq[128];
    lwq[t] = Wq[blk * 128 + t];
    __syncthreads();
    float acc = 0.f;
#pragma unroll 8
    for (int d = 0; d < 128; ++d) acc += Wk[t * 128 + d] * lwq[d];
    Mt[blk * 128 + t] = SQRT_C * acc;
  } else if (blk < 256) {
    int c = blk - 128;
    float acc = 0.f;
#pragma unroll 8
    for (int e = 0; e < 128; ++e) acc += Wv[c * 128 + e] * Wout[e * 128 + t];
    W2[c * 128 + t] = acc;
  } else if (blk == 256) {
    float au = 0.f, ab = 0.f;
    for (int d = 0; d < 128; ++d) au += Wk[t * 128 + d] * bq[d];
    u[t] = SQRT_C * au;
    for (int e = 0; e < 128; ++e) ab += bv[e] * Wout[e * 128 + t];
    b2[t] = ab + bout[t];
  } else {
#pragma unroll
    for (int j = 0; j < 24; ++j) Wofft[j * 128 + t] = Woff[t * 24 + j];
  }
}

// ---------------- bilinear combo: 4 byte-offsets + 4 corner weights ----------
__device__ __forceinline__ void make_combo(float cx, float cy,
                                           int4* oi, float4* ow) {
  float fx = fminf(fmaxf((cx + 1.f) * 31.5f, 0.f), 63.f);
  float fy = fminf(fmaxf((cy + 1.f) * 31.5f, 0.f), 63.f);
  float x0f = floorf(fx), y0f = floorf(fy);
  int x0 = (int)x0f, y0 = (int)y0f;
  int x1 = min(x0 + 1, 63), y1 = min(y0 + 1, 63);
  float wx = fx - x0f, wy = fy - y0f;
  int r0 = y0 << 15, r1 = y1 << 15;     // hw-row stride = 64*128*4 B
  int cb0 = x0 << 9, cb1 = x1 << 9;     // hw-col stride = 128*4 B
  *oi = make_int4(r0 + cb0, r0 + cb1, r1 + cb0, r1 + cb1);
  float wxy = wx * wy;
  *ow = make_float4(1.f - wx - wy + wxy, wx - wxy, wy - wxy, wxy);
}

__device__ __forceinline__ float ldf(const char* p, int off) {
  return *(const float*)(p + off);
}

// ---------------- main fused kernel v12 -------------------------------------
// v9's exact structure (128 threads / 2 waves, 8 queries, thread = channel,
// Morton-sorted queries, LDS union) with Phase C restructured as TWO
// barrier-free passes: pass 1 computes all 8 queries' logits (samples
// discarded), ONE barrier, pass 2 redundant softmax + cache-hot corner
// RELOAD for the attn-weighted sum. 15 block barriers -> 8.
__global__ __launch_bounds__(128, 4) void deform_attn12(
    const float* __restrict__ qpos, const int* __restrict__ sidx,
    const float* __restrict__ pT,
    const float* __restrict__ Mt, const float* __restrict__ u,
    const float* __restrict__ W2, const float* __restrict__ bias2,
    const float* __restrict__ Wofft, const float* __restrict__ boff,
    float* __restrict__ out) {
  const int tid = threadIdx.x;
  const int c = tid;
  const int l = tid & 63;
  const int wv = tid >> 6;
  const int bid = blockIdx.x;
  const int b = bid & 7;               // batch -> XCD locality heuristic
  const int n0 = (bid >> 3) * 8;

  __shared__ int snidx[8];
  __shared__ float spos[24];
  __shared__ int4   sfi[24];           // feature combos [p][q]
  __shared__ float4 sfw[24];
  __shared__ int4   sci[192];          // aux combos [p][q][j] = p*64+q*8+j
  __shared__ float4 scw[192];
  __shared__ __align__(16) float sbuf[CC * 8];    // features, then w (union)
  __shared__ float soff[8][24];
  __shared__ float sred[8][2][8];

  if (tid < 8) snidx[tid] = sidx[b * NN + n0 + tid];
  __syncthreads();
  if (tid < 24) {
    int q = tid / 3, comp = tid - q * 3;
    spos[tid] = qpos[((size_t)b * NN + snidx[q]) * 3 + comp];
  }
  __syncthreads();

  const char* pb0 = (const char*)(pT + (size_t)(0 * BB + b) * PLANE_B + c);
  const char* pb1 = (const char*)(pT + (size_t)(1 * BB + b) * PLANE_B + c);
  const char* pb2 = (const char*)(pT + (size_t)(2 * BB + b) * PLANE_B + c);

  // ---- feature combos (24 = 3 planes x 8 queries) ----
  if (tid < 24) {
    int p = tid >> 3, q = tid & 7;
    float px = spos[q * 3 + 0], py = spos[q * 3 + 1], pz = spos[q * 3 + 2];
    float cx = (p == 2) ? py : px;
    float cy = (p == 1) ? py : pz;
    make_combo(cx, cy, &sfi[tid], &sfw[tid]);
  }
  __syncthreads();

  // ---- Phase A: feature sampling (1 channel per thread, 8 queries) ----
  float featr[8];
#pragma unroll
  for (int q = 0; q < 8; ++q) {
    float f = 0.f;
#pragma unroll
    for (int p = 0; p < 3; ++p) {
      int4 oi = sfi[p * 8 + q];
      float4 w = sfw[p * 8 + q];
      const char* base = (p == 0) ? pb0 : (p == 1) ? pb1 : pb2;
      f += w.x * ldf(base, oi.x) + w.y * ldf(base, oi.y)
         + w.z * ldf(base, oi.z) + w.w * ldf(base, oi.w);
    }
    featr[q] = f;
    sbuf[c * 8 + q] = f;
  }
  __syncthreads();

  // ---- Phase B: qk matvec with fused M ----
  float qk[8];
  {
    float uc = u[c];
#pragma unroll
    for (int q = 0; q < 8; ++q) qk[q] = uc;
#pragma unroll 4
    for (int cp = 0; cp < CC; ++cp) {
      float m = Mt[cp * CC + c];
      float4 f0 = *(const float4*)&sbuf[cp * 8];
      float4 f1 = *(const float4*)&sbuf[cp * 8 + 4];
      qk[0] += m * f0.x; qk[1] += m * f0.y; qk[2] += m * f0.z; qk[3] += m * f0.w;
      qk[4] += m * f1.x; qk[5] += m * f1.y; qk[6] += m * f1.z; qk[7] += m * f1.w;
    }
  }

  // ---- Phase B2: deformable offsets (192 dot products over 128 threads) ----
#pragma unroll
  for (int rep = 0; rep < 2; ++rep) {
    int m = rep * 128 + tid;
    if (m < 192) {
      int q = m / 24;
      int t24 = m - q * 24;
      float acc = boff[t24];
      const float* wrow = Wofft + t24 * 128;
#pragma unroll 4
      for (int cp = 0; cp < CC; ++cp) acc += sbuf[cp * 8 + q] * wrow[cp];
      soff[q][t24] = acc;
    }
  }
  __syncthreads();
  // sbuf's feature contents are dead from here (residual kept in featr[]).

  // ---- aux combos (192 = 3 planes x 8 q x 8 j) ----
#pragma unroll
  for (int rep = 0; rep < 2; ++rep) {
    int m = rep * 128 + tid;             // m = p*64 + q*8 + j
    if (m < 192) {
      int p = m >> 6, q = (m >> 3) & 7, j = m & 7;
      float ox = spos[q * 3 + 0] + soff[q][j * 3 + 0];
      float oy = spos[q * 3 + 1] + soff[q][j * 3 + 1];
      float oz = spos[q * 3 + 2] + soff[q][j * 3 + 2];
      float cx = (p == 2) ? oy : ox;
      float cy = (p == 1) ? oy : oz;
      make_combo(cx, cy, &sci[m], &scw[m]);
    }
  }
  __syncthreads();

  // ---- Phase C pass 1: logits for ALL 8 queries, ZERO barriers ----
  const int lb0 = l & 1, lb1 = (l >> 1) & 1, lb2 = (l >> 2) & 1;
#pragma unroll
  for (int q = 0; q < 8; ++q) {
    float part[8];
#pragma unroll
    for (int j = 0; j < 8; ++j) {
      float a = 0.f;
#pragma unroll
      for (int p = 0; p < 3; ++p) {
        int idx = p * 64 + q * 8 + j;
        int4 oi = sci[idx];
        float4 w = scw[idx];
        const char* base = (p == 0) ? pb0 : (p == 1) ? pb1 : pb2;
        a += w.x * ldf(base, oi.x) + w.y * ldf(base, oi.y)
           + w.z * ldf(base, oi.z) + w.w * ldf(base, oi.w);
      }
      part[j] = a * qk[q];               // sample value discarded
    }
    // multi-value butterfly: 8 logits reduced across 64 lanes in 10 shuffles
    float s2[4];
#pragma unroll
    for (int k = 0; k < 4; ++k) {
      float pa = part[2 * k], pb_ = part[2 * k + 1];
      float snd = lb0 ? pa : pb_;
      float kp  = lb0 ? pb_ : pa;
      s2[k] = kp + __shfl_xor(snd, 1);
    }
    float s4[2];
#pragma unroll
    for (int k = 0; k < 2; ++k) {
      float pa = s2[2 * k], pb_ = s2[2 * k + 1];
      float snd = lb1 ? pa : pb_;
      float kp  = lb1 ? pb_ : pa;
      s4[k] = kp + __shfl_xor(snd, 2);
    }
    float s8;
    {
      float snd = lb2 ? s4[0] : s4[1];
      float kp  = lb2 ? s4[1] : s4[0];
      s8 = kp + __shfl_xor(snd, 4);
    }
    s8 += __shfl_xor(s8, 8);
    s8 += __shfl_xor(s8, 16);
    s8 += __shfl_xor(s8, 32);
    if (l < 8) sred[q][wv][l] = s8;      // lane l holds logit j = l (l<8)
  }
  __syncthreads();                       // the ONLY Phase C barrier

  // ---- Phase C pass 2: softmax (redundant per thread, as v9) + reload ----
#pragma unroll
  for (int q = 0; q < 8; ++q) {
    float sim[8];
#pragma unroll
    for (int j = 0; j < 8; ++j) sim[j] = sred[q][0][j] + sred[q][1][j];
    float mx = fmaxf(fmaxf(fmaxf(sim[0], sim[1]), fmaxf(sim[2], sim[3])),
                     fmaxf(fmaxf(sim[4], sim[5]), fmaxf(sim[6], sim[7])));
    float den = 0.f;
#pragma unroll
    for (int j = 0; j < 8; ++j) { sim[j] = __expf(sim[j] - mx); den += sim[j]; }
    float inv = 1.f / den;
    float w = 0.f;
#pragma unroll
    for (int j = 0; j < 8; ++j) {
      float a = 0.f;
#pragma unroll
      for (int p = 0; p < 3; ++p) {
        int idx = p * 64 + q * 8 + j;
        int4 oi = sci[idx];
        float4 ww = scw[idx];
        const char* base = (p == 0) ? pb0 : (p == 1) ? pb1 : pb2;
        a += ww.x * ldf(base, oi.x) + ww.y * ldf(base, oi.y)
           + ww.z * ldf(base, oi.z) + ww.w * ldf(base, oi.w);
      }
      w += sim[j] * a;                   // reload is L1/L2-hot (sorted block)
    }
    sbuf[c * 8 + q] = w * inv;           // overwrite dead feature column q
  }
  __syncthreads();

  // ---- Phase F: out = w @ (Wv@Wout) + b2 + feature ----
  float o[8];
  {
    float bb = bias2[c];
#pragma unroll
    for (int q = 0; q < 8; ++q) o[q] = bb;
#pragma unroll 4
    for (int cp = 0; cp < CC; ++cp) {
      float m = W2[cp * CC + c];
      float4 f0 = *(const float4*)&sbuf[cp * 8];
      float4 f1 = *(const float4*)&sbuf[cp * 8 + 4];
      o[0] += m * f0.x; o[1] += m * f0.y; o[2] += m * f0.z; o[3] += m * f0.w;
      o[4] += m * f1.x; o[5] += m * f1.y; o[6] += m * f1.z; o[7] += m * f1.w;
    }
  }
#pragma unroll
  for (int q = 0; q < 8; ++q) {
    out[((size_t)b * NN + snidx[q]) * CC + c] = o[q] + featr[q];
  }
}

// ---------------- last-resort fallback (no workspace) -----------------------
__device__ __forceinline__ float bil(const float* __restrict__ base,
                                     float cx, float cy, int es, int rs) {
  float fx = fminf(fmaxf((cx + 1.f) * 31.5f, 0.f), 63.f);
  float fy = fminf(fmaxf((cy + 1.f) * 31.5f, 0.f), 63.f);
  float x0f = floorf(fx), y0f = floorf(fy);
  int x0 = (int)x0f, y0 = (int)y0f;
  int x1 = min(x0 + 1, 63), y1 = min(y0 + 1, 63);
  float wx = fx - x0f, wy = fy - y0f;
  const float* r0 = base + y0 * rs;
  const float* r1 = base + y1 * rs;
  float f00 = r0[x0 * es], f01 = r0[x1 * es];
  float f10 = r1[x0 * es], f11 = r1[x1 * es];
  float top = f00 + (f01 - f00) * wx;
  float bot = f10 + (f11 - f10) * wx;
  return top + (bot - top) * wy;
}

__global__ __launch_bounds__(128) void deform_attn_fb(
    const float* __restrict__ qpos,
    const float* __restrict__ pxz, const float* __restrict__ pxy,
    const float* __restrict__ pyz,
    const float* __restrict__ Mt, const float* __restrict__ u,
    const float* __restrict__ W2, const float* __restrict__ b2,
    const float* __restrict__ Woff, const float* __restrict__ boff,
    float* __restrict__ out) {
  const int tid = threadIdx.x;
  const int c = tid;
  const int bid = blockIdx.x;
  const int b = bid & 7;
  const int n0 = (bid >> 3) * 8;
  const int es = 1, rs = HH;
  const float* bxz = pxz + (size_t)(b * CC + c) * HW;
  const float* bxy = pxy + (size_t)(b * CC + c) * HW;
  const float* byz = pyz + (size_t)(b * CC + c) * HW;

  __shared__ __align__(16) float sfeat[CC * 8];
  __shared__ __align__(16) float swv[CC * 8];
  __shared__ float spos[24];
  __shared__ float soff[8][24];
  __shared__ float sred[8][2][8];

  if (tid < 24) spos[tid] = qpos[(size_t)(b * NN + n0) * 3 + tid];
  __syncthreads();
#pragma unroll
  for (int q = 0; q < 8; ++q) {
    float px = spos[q*3+0], py = spos[q*3+1], pz = spos[q*3+2];
    sfeat[c*8+q] = bil(bxz,px,pz,es,rs)+bil(bxy,px,py,es,rs)+bil(byz,py,pz,es,rs);
  }
  __syncthreads();
  float qk[8];
  {
    float uc = u[c];
#pragma unroll
    for (int q = 0; q < 8; ++q) qk[q] = uc;
    for (int cp = 0; cp < CC; ++cp) {
      float m = Mt[cp*CC+c];
#pragma unroll
      for (int q = 0; q < 8; ++q) qk[q] += m * sfeat[cp*8+q];
    }
  }
  if (tid < 120) {
    int q = tid/24, j = tid%24;
    float acc = boff[j];
    for (int cp = 0; cp < CC; ++cp) acc += sfeat[cp*8+q]*Woff[cp*24+j];
    soff[q][j] = acc;
  }
  if (tid < 72) {
    int q = 5+tid/24, j = tid%24;
    float acc = boff[j];
    for (int cp = 0; cp < CC; ++cp) acc += sfeat[cp*8+q]*Woff[cp*24+j];
    soff[q][j] = acc;
  }
  __syncthreads();
  const int wvid = tid >> 6;
  for (int q = 0; q < 8; ++q) {
    float px = spos[q*3+0], py = spos[q*3+1], pz = spos[q*3+2];
    float a8[8];
#pragma unroll
    for (int j = 0; j < 8; ++j) {
      float ox = px+soff[q][j*3+0], oy = py+soff[q][j*3+1], oz = pz+soff[q][j*3+2];
      float a = bil(bxz,ox,oz,es,rs)+bil(bxy,ox,oy,es,rs)+bil(byz,oy,oz,es,rs);
      a8[j] = a;
      float p = a * qk[q];
#pragma unroll
      for (int m = 1; m < 64; m <<= 1) p += __shfl_xor(p, m);
      if ((tid & 63) == 0) sred[q][wvid][j] = p;
    }
    __syncthreads();
    float attn[8], mx = -INFINITY;
#pragma unroll
    for (int j = 0; j < 8; ++j) { attn[j] = sred[q][0][j]+sred[q][1][j]; mx = fmaxf(mx, attn[j]); }
    float den = 0.f;
#pragma unroll
    for (int j = 0; j < 8; ++j) { attn[j] = __expf(attn[j]-mx); den += attn[j]; }
    float inv = 1.f/den, w = 0.f;
#pragma unroll
    for (int j = 0; j < 8; ++j) w += attn[j]*a8[j];
    swv[c*8+q] = w*inv;
  }
  __syncthreads();
  float o[8];
  {
    float bb = b2[c];
#pragma unroll
    for (int q = 0; q < 8; ++q) o[q] = bb;
    for (int cp = 0; cp < CC; ++cp) {
      float wv2 = W2[cp*CC+c];
#pragma unroll
      for (int q = 0; q < 8; ++q) o[q] += wv2 * swv[cp*8+q];
    }
  }
#pragma unroll
  for (int q = 0; q < 8; ++q)
    out[(size_t)(b*NN+n0+q)*CC+c] = o[q] + sfeat[c*8+q];
}

extern "C" void kernel_launch(void* const* d_in, const int* in_sizes, int n_in,
                              void* d_out, int out_size, void* d_ws, size_t ws_size,
                              hipStream_t stream) {
  const float* qpos = (const float*)d_in[0];
  const float* pxz  = (const float*)d_in[1];
  const float* pxy  = (const float*)d_in[2];
  const float* pyz  = (const float*)d_in[3];
  const float* Wq   = (const float*)d_in[4];
  const float* bq   = (const float*)d_in[5];
  const float* Wk   = (const float*)d_in[6];
  // d_in[7] = bk: q.bk is constant over the S axis -> cancels in softmax
  const float* Wv   = (const float*)d_in[8];
  const float* bv   = (const float*)d_in[9];
  const float* Wout = (const float*)d_in[10];
  const float* bout = (const float*)d_in[11];
  const float* Woff = (const float*)d_in[12];
  const float* boff = (const float*)d_in[13];
  float* out = (float*)d_out;

  float* w = (float*)d_ws;
  const size_t nT = (size_t)3 * BB * HW * CC;
  const size_t matFloats = 16384 + 128 + 16384 + 128 + 24 * 128;
  const size_t sidxInts = (size_t)BB * NN;
  bool tp = ws_size >= (nT + matFloats + sidxInts) * sizeof(float);

  float* wsT  = w;
  float* wsMt = tp ? (w + nT) : w;
  float* wsU  = wsMt + 16384;
  float* wsW2 = wsU + 128;
  float* wsB2 = wsW2 + 16384;
  float* wsWofft = wsB2 + 128;
  int*   wsSidx  = (int*)(wsWofft + 24 * 128);

  prep_mats<<<258, 128, 0, stream>>>(Wq, bq, Wk, Wv, bv, Wout, bout, Woff,
                                     wsMt, wsU, wsW2, wsB2, wsWofft);
  if (tp) {
    sort_queries<<<BB, 1024, 0, stream>>>(qpos, wsSidx);
    transpose_planes<<<3 * BB * (HW / 16), 128, 0, stream>>>(pxz, pxy, pyz, wsT);
    deform_attn12<<<(BB * NN) / 8, 128, 0, stream>>>(
        qpos, wsSidx, wsT, wsMt, wsU, wsW2, wsB2, wsWofft, boff, out);
  } else {
    deform_attn_fb<<<(BB * NN) / 8, 128, 0, stream>>>(
        qpos, pxz, pxy, pyz, wsMt, wsU, wsW2, wsB2, Woff, boff, out);
  }
}

// Round 13
// 202.165 us; speedup vs baseline: 1.2706x; 1.2530x over previous
//
#include <hip/hip_runtime.h>
#include <math.h>

#define BB 8
#define NN 4096
#define CC 128
#define SS 8
#define HH 64
#define HW 4096              // 64*64
#define PLANE_B (HW*CC)      // floats per (plane,batch) in transposed layout
#define SQRT_C 11.3137084989847603904f

// ---------------- transpose planes [B,C,H,W] -> [plane,B,HW,C] ----------------
__global__ __launch_bounds__(128) void transpose_planes(
    const float* __restrict__ pxz, const float* __restrict__ pxy,
    const float* __restrict__ pyz, float* __restrict__ dst) {
  int bid = blockIdx.x;
  int c   = threadIdx.x;
  int hw0 = (bid & 255) * 16;
  int b   = (bid >> 8) & 7;
  int p   = bid >> 11;
  const float* src = (p == 0) ? pxz : (p == 1) ? pxy : pyz;
  const float4* s4 = (const float4*)(src + (size_t)(b * CC + c) * HW + hw0);
  float4 v0 = s4[0], v1 = s4[1], v2 = s4[2], v3 = s4[3];
  float vals[16];
  vals[0]=v0.x; vals[1]=v0.y; vals[2]=v0.z; vals[3]=v0.w;
  vals[4]=v1.x; vals[5]=v1.y; vals[6]=v1.z; vals[7]=v1.w;
  vals[8]=v2.x; vals[9]=v2.y; vals[10]=v2.z; vals[11]=v2.w;
  vals[12]=v3.x; vals[13]=v3.y; vals[14]=v3.z; vals[15]=v3.w;
  float* d = dst + (size_t)(p * BB + b) * PLANE_B + (size_t)hw0 * CC + c;
#pragma unroll
  for (int i = 0; i < 16; ++i) d[i * CC] = vals[i];
}

// ------------- per-batch spatial clustering: counting sort by Morton cell ----
// Each query's result is computed independently of its blockmates, so any
// permutation of query->block assignment is output-identical. Order within a
// cell comes from LDS atomics (nondeterministic) but that only changes
// grouping, never per-query arithmetic.
__device__ __forceinline__ int morton3_3(int cx, int cy, int cz) {
  int m = 0;
#pragma unroll
  for (int k = 0; k < 3; ++k) {
    m |= ((cx >> k) & 1) << (3 * k);
    m |= ((cy >> k) & 1) << (3 * k + 1);
    m |= ((cz >> k) & 1) << (3 * k + 2);
  }
  return m;
}

__global__ __launch_bounds__(1024) void sort_queries(
    const float* __restrict__ qpos, int* __restrict__ sidx) {
  const int b = blockIdx.x;
  const int t = threadIdx.x;
  __shared__ unsigned short scell[NN];
  __shared__ int hist[512];
  __shared__ int tmp[512];
  __shared__ int cur[512];
  if (t < 512) hist[t] = 0;
  __syncthreads();
  for (int i = t; i < NN; i += 1024) {
    const float* qp = qpos + ((size_t)b * NN + i) * 3;
    float x = qp[0], y = qp[1], z = qp[2];
    int cx = min(7, max(0, (int)((x + 1.f) * 4.f)));
    int cy = min(7, max(0, (int)((y + 1.f) * 4.f)));
    int cz = min(7, max(0, (int)((z + 1.f) * 4.f)));
    int cell = morton3_3(cx, cy, cz);
    scell[i] = (unsigned short)cell;
    atomicAdd(&hist[cell], 1);
  }
  __syncthreads();
  if (t < 512) tmp[t] = hist[t];
  __syncthreads();
  for (int off = 1; off < 512; off <<= 1) {     // inclusive scan
    int v = 0;
    if (t < 512 && t >= off) v = tmp[t - off];
    __syncthreads();
    if (t < 512) tmp[t] += v;
    __syncthreads();
  }
  if (t < 512) cur[t] = tmp[t] - hist[t];       // exclusive
  __syncthreads();
  for (int i = t; i < NN; i += 1024) {
    int cell = scell[i];
    int pos = atomicAdd(&cur[cell], 1);
    sidx[b * NN + pos] = i;
  }
}

// ---------------- precompute fused matrices ----------------
// Mt[c'][c] = sqrt(C) * sum_d Wk[c,d]*Wq[c',d]
// u[c]     = sqrt(C) * sum_d Wk[c,d]*bq[d]
// W2[c][d] = sum_e Wv[c,e]*Wout[e,d]
// b2[d]    = sum_e bv[e]*Wout[e,d] + bout[d]
// Wofft[j][c] = Woff[c][j]
__global__ __launch_bounds__(128) void prep_mats(
    const float* __restrict__ Wq, const float* __restrict__ bq,
    const float* __restrict__ Wk,
    const float* __restrict__ Wv, const float* __restrict__ bv,
    const float* __restrict__ Wout, const float* __restrict__ bout,
    const float* __restrict__ Woff,
    float* __restrict__ Mt, float* __restrict__ u,
    float* __restrict__ W2, float* __restrict__ b2,
    float* __restrict__ Wofft) {
  int t = threadIdx.x;
  int blk = blockIdx.x;
  if (blk < 128) {                 // Mt row c' = blk, thread = c
    __shared__ float lwq[128];
    lwq[t] = Wq[blk * 128 + t];
    __syncthreads();
    float acc = 0.f;
#pragma unroll 8
    for (int d = 0; d < 128; ++d) acc += Wk[t * 128 + d] * lwq[d];
    Mt[blk * 128 + t] = SQRT_C * acc;
  } else if (blk < 256) {          // W2 row c = blk-128, thread = d
    int c = blk - 128;
    float acc = 0.f;
#pragma unroll 8
    for (int e = 0; e < 128; ++e) acc += Wv[c * 128 + e] * Wout[e * 128 + t];
    W2[c * 128 + t] = acc;
  } else if (blk == 256) {         // u and b2
    float au = 0.f, ab = 0.f;
    for (int d = 0; d < 128; ++d) au += Wk[t * 128 + d] * bq[d];
    u[t] = SQRT_C * au;
    for (int e = 0; e < 128; ++e) ab += bv[e] * Wout[e * 128 + t];
    b2[t] = ab + bout[t];
  } else {                         // Woff transpose
#pragma unroll
    for (int j = 0; j < 24; ++j) Wofft[j * 128 + t] = Woff[t * 24 + j];
  }
}

// ---------------- bilinear combo: 4 byte-offsets + 4 corner weights ----------
__device__ __forceinline__ void make_combo(float cx, float cy,
                                           int4* oi, float4* ow) {
  float fx = fminf(fmaxf((cx + 1.f) * 31.5f, 0.f), 63.f);
  float fy = fminf(fmaxf((cy + 1.f) * 31.5f, 0.f), 63.f);
  float x0f = floorf(fx), y0f = floorf(fy);
  int x0 = (int)x0f, y0 = (int)y0f;
  int x1 = min(x0 + 1, 63), y1 = min(y0 + 1, 63);
  float wx = fx - x0f, wy = fy - y0f;
  int r0 = y0 << 15, r1 = y1 << 15;     // hw-row stride = 64*128*4 B
  int cb0 = x0 << 9, cb1 = x1 << 9;     // hw-col stride = 128*4 B
  *oi = make_int4(r0 + cb0, r0 + cb1, r1 + cb0, r1 + cb1);
  float wxy = wx * wy;
  *ow = make_float4(1.f - wx - wy + wxy, wx - wxy, wy - wxy, wxy);
}

__device__ __forceinline__ float ldf(const char* p, int off) {
  return *(const float*)(p + off);
}

// ---------------- main fused kernel v9 (final) ------------------------------
// 128 threads / 2 waves, 8 Morton-clustered queries per block, thread =
// channel, LDS combos, butterfly logit reduction, LDS union (sbuf holds
// features then weighted-values; residual in featr regs).
__global__ __launch_bounds__(128, 4) void deform_attn9(
    const float* __restrict__ qpos, const int* __restrict__ sidx,
    const float* __restrict__ pT,
    const float* __restrict__ Mt, const float* __restrict__ u,
    const float* __restrict__ W2, const float* __restrict__ bias2,
    const float* __restrict__ Wofft, const float* __restrict__ boff,
    float* __restrict__ out) {
  const int tid = threadIdx.x;
  const int c = tid;
  const int l = tid & 63;
  const int wv = tid >> 6;
  const int bid = blockIdx.x;
  const int b = bid & 7;               // batch -> XCD locality heuristic
  const int n0 = (bid >> 3) * 8;

  __shared__ int snidx[8];
  __shared__ float spos[24];
  __shared__ int4   sfi[24];           // feature combos [p][q]
  __shared__ float4 sfw[24];
  __shared__ int4   sci[192];          // aux combos [p][q][j] = p*64+q*8+j
  __shared__ float4 scw[192];
  __shared__ __align__(16) float sbuf[CC * 8];    // features, then w (union)
  __shared__ float soff[8][24];
  __shared__ float sred[8][2][8];

  if (tid < 8) snidx[tid] = sidx[b * NN + n0 + tid];
  __syncthreads();
  if (tid < 24) {
    int q = tid / 3, comp = tid - q * 3;
    spos[tid] = qpos[((size_t)b * NN + snidx[q]) * 3 + comp];
  }
  __syncthreads();

  const char* pb0 = (const char*)(pT + (size_t)(0 * BB + b) * PLANE_B + c);
  const char* pb1 = (const char*)(pT + (size_t)(1 * BB + b) * PLANE_B + c);
  const char* pb2 = (const char*)(pT + (size_t)(2 * BB + b) * PLANE_B + c);

  // ---- feature combos (24 = 3 planes x 8 queries) ----
  if (tid < 24) {
    int p = tid >> 3, q = tid & 7;
    float px = spos[q * 3 + 0], py = spos[q * 3 + 1], pz = spos[q * 3 + 2];
    float cx = (p == 2) ? py : px;
    float cy = (p == 1) ? py : pz;
    make_combo(cx, cy, &sfi[tid], &sfw[tid]);
  }
  __syncthreads();

  // ---- Phase A: feature sampling (1 channel per thread, 8 queries) ----
  float featr[8];
#pragma unroll
  for (int q = 0; q < 8; ++q) {
    float f = 0.f;
#pragma unroll
    for (int p = 0; p < 3; ++p) {
      int4 oi = sfi[p * 8 + q];
      float4 w = sfw[p * 8 + q];
      const char* base = (p == 0) ? pb0 : (p == 1) ? pb1 : pb2;
      f += w.x * ldf(base, oi.x) + w.y * ldf(base, oi.y)
         + w.z * ldf(base, oi.z) + w.w * ldf(base, oi.w);
    }
    featr[q] = f;
    sbuf[c * 8 + q] = f;
  }
  __syncthreads();

  // ---- Phase B: qk matvec with fused M ----
  float qk[8];
  {
    float uc = u[c];
#pragma unroll
    for (int q = 0; q < 8; ++q) qk[q] = uc;
#pragma unroll 4
    for (int cp = 0; cp < CC; ++cp) {
      float m = Mt[cp * CC + c];
      float4 f0 = *(const float4*)&sbuf[cp * 8];
      float4 f1 = *(const float4*)&sbuf[cp * 8 + 4];
      qk[0] += m * f0.x; qk[1] += m * f0.y; qk[2] += m * f0.z; qk[3] += m * f0.w;
      qk[4] += m * f1.x; qk[5] += m * f1.y; qk[6] += m * f1.z; qk[7] += m * f1.w;
    }
  }

  // ---- Phase B2: deformable offsets (192 dot products over 128 threads) ----
#pragma unroll
  for (int rep = 0; rep < 2; ++rep) {
    int m = rep * 128 + tid;
    if (m < 192) {
      int q = m / 24;
      int t24 = m - q * 24;
      float acc = boff[t24];
      const float* wrow = Wofft + t24 * 128;
#pragma unroll 4
      for (int cp = 0; cp < CC; ++cp) acc += sbuf[cp * 8 + q] * wrow[cp];
      soff[q][t24] = acc;
    }
  }
  __syncthreads();
  // sbuf's feature contents are dead from here (residual kept in featr[]).

  // ---- aux combos (192 = 3 planes x 8 q x 8 j) ----
#pragma unroll
  for (int rep = 0; rep < 2; ++rep) {
    int m = rep * 128 + tid;             // m = p*64 + q*8 + j
    if (m < 192) {
      int p = m >> 6, q = (m >> 3) & 7, j = m & 7;
      float ox = spos[q * 3 + 0] + soff[q][j * 3 + 0];
      float oy = spos[q * 3 + 1] + soff[q][j * 3 + 1];
      float oz = spos[q * 3 + 2] + soff[q][j * 3 + 2];
      float cx = (p == 2) ? oy : ox;
      float cy = (p == 1) ? oy : oz;
      make_combo(cx, cy, &sci[m], &scw[m]);
    }
  }
  __syncthreads();

  // ---- Phase C: aux sampling + logits (butterfly) + softmax + weighted sum --
  const int lb0 = l & 1, lb1 = (l >> 1) & 1, lb2 = (l >> 2) & 1;
#pragma unroll
  for (int q = 0; q < 8; ++q) {
    float a8[8], part[8];
#pragma unroll
    for (int j = 0; j < 8; ++j) {
      float a = 0.f;
#pragma unroll
      for (int p = 0; p < 3; ++p) {
        int idx = p * 64 + q * 8 + j;
        int4 oi = sci[idx];
        float4 w = scw[idx];
        const char* base = (p == 0) ? pb0 : (p == 1) ? pb1 : pb2;
        a += w.x * ldf(base, oi.x) + w.y * ldf(base, oi.y)
           + w.z * ldf(base, oi.z) + w.w * ldf(base, oi.w);
      }
      a8[j] = a;
      part[j] = a * qk[q];
    }
    // multi-value butterfly: 8 logits reduced across 64 lanes in 10 shuffles
    float s2[4];
#pragma unroll
    for (int k = 0; k < 4; ++k) {
      float pa = part[2 * k], pb_ = part[2 * k + 1];
      float snd = lb0 ? pa : pb_;
      float kp  = lb0 ? pb_ : pa;
      s2[k] = kp + __shfl_xor(snd, 1);
    }
    float s4[2];
#pragma unroll
    for (int k = 0; k < 2; ++k) {
      float pa = s2[2 * k], pb_ = s2[2 * k + 1];
      float snd = lb1 ? pa : pb_;
      float kp  = lb1 ? pb_ : pa;
      s4[k] = kp + __shfl_xor(snd, 2);
    }
    float s8;
    {
      float snd = lb2 ? s4[0] : s4[1];
      float kp  = lb2 ? s4[1] : s4[0];
      s8 = kp + __shfl_xor(snd, 4);
    }
    s8 += __shfl_xor(s8, 8);
    s8 += __shfl_xor(s8, 16);
    s8 += __shfl_xor(s8, 32);
    if (l < 8) sred[q][wv][l] = s8;      // lane l holds logit j = l (l<8)
    __syncthreads();
    float sim[8];
#pragma unroll
    for (int j = 0; j < 8; ++j) sim[j] = sred[q][0][j] + sred[q][1][j];
    float mx = fmaxf(fmaxf(fmaxf(sim[0], sim[1]), fmaxf(sim[2], sim[3])),
                     fmaxf(fmaxf(sim[4], sim[5]), fmaxf(sim[6], sim[7])));
    float den = 0.f;
#pragma unroll
    for (int j = 0; j < 8; ++j) { sim[j] = __expf(sim[j] - mx); den += sim[j]; }
    float inv = 1.f / den;
    float w = 0.f;
#pragma unroll
    for (int j = 0; j < 8; ++j) w += sim[j] * a8[j];
    sbuf[c * 8 + q] = w * inv;           // overwrite dead feature column q
  }
  __syncthreads();

  // ---- Phase F: out = w @ (Wv@Wout) + b2 + feature ----
  float o[8];
  {
    float bb = bias2[c];
#pragma unroll
    for (int q = 0; q < 8; ++q) o[q] = bb;
#pragma unroll 4
    for (int cp = 0; cp < CC; ++cp) {
      float m = W2[cp * CC + c];
      float4 f0 = *(const float4*)&sbuf[cp * 8];
      float4 f1 = *(const float4*)&sbuf[cp * 8 + 4];
      o[0] += m * f0.x; o[1] += m * f0.y; o[2] += m * f0.z; o[3] += m * f0.w;
      o[4] += m * f1.x; o[5] += m * f1.y; o[6] += m * f1.z; o[7] += m * f1.w;
    }
  }
#pragma unroll
  for (int q = 0; q < 8; ++q) {
    out[((size_t)b * NN + snidx[q]) * CC + c] = o[q] + featr[q];
  }
}

// ---------------- fallback (no workspace for transposed planes) -------------
__device__ __forceinline__ float bil(const float* __restrict__ base,
                                     float cx, float cy, int es, int rs) {
  float fx = fminf(fmaxf((cx + 1.f) * 31.5f, 0.f), 63.f);
  float fy = fminf(fmaxf((cy + 1.f) * 31.5f, 0.f), 63.f);
  float x0f = floorf(fx), y0f = floorf(fy);
  int x0 = (int)x0f, y0 = (int)y0f;
  int x1 = min(x0 + 1, 63), y1 = min(y0 + 1, 63);
  float wx = fx - x0f, wy = fy - y0f;
  const float* r0 = base + y0 * rs;
  const float* r1 = base + y1 * rs;
  float f00 = r0[x0 * es], f01 = r0[x1 * es];
  float f10 = r1[x0 * es], f11 = r1[x1 * es];
  float top = f00 + (f01 - f00) * wx;
  float bot = f10 + (f11 - f10) * wx;
  return top + (bot - top) * wy;
}

__global__ __launch_bounds__(128) void deform_attn_fb(
    const float* __restrict__ qpos,
    const float* __restrict__ pxz, const float* __restrict__ pxy,
    const float* __restrict__ pyz,
    const float* __restrict__ Mt, const float* __restrict__ u,
    const float* __restrict__ W2, const float* __restrict__ b2,
    const float* __restrict__ Woff, const float* __restrict__ boff,
    float* __restrict__ out) {
  const int tid = threadIdx.x;
  const int c = tid;
  const int bid = blockIdx.x;
  const int b = bid & 7;
  const int n0 = (bid >> 3) * 8;
  const int es = 1, rs = HH;
  const float* bxz = pxz + (size_t)(b * CC + c) * HW;
  const float* bxy = pxy + (size_t)(b * CC + c) * HW;
  const float* byz = pyz + (size_t)(b * CC + c) * HW;

  __shared__ __align__(16) float sfeat[CC * 8];
  __shared__ __align__(16) float swv[CC * 8];
  __shared__ float spos[24];
  __shared__ float soff[8][24];
  __shared__ float sred[8][2][8];

  if (tid < 24) spos[tid] = qpos[(size_t)(b * NN + n0) * 3 + tid];
  __syncthreads();
#pragma unroll
  for (int q = 0; q < 8; ++q) {
    float px = spos[q*3+0], py = spos[q*3+1], pz = spos[q*3+2];
    sfeat[c*8+q] = bil(bxz,px,pz,es,rs)+bil(bxy,px,py,es,rs)+bil(byz,py,pz,es,rs);
  }
  __syncthreads();
  float qk[8];
  {
    float uc = u[c];
#pragma unroll
    for (int q = 0; q < 8; ++q) qk[q] = uc;
    for (int cp = 0; cp < CC; ++cp) {
      float m = Mt[cp*CC+c];
#pragma unroll
      for (int q = 0; q < 8; ++q) qk[q] += m * sfeat[cp*8+q];
    }
  }
  if (tid < 120) {
    int q = tid/24, j = tid%24;
    float acc = boff[j];
    for (int cp = 0; cp < CC; ++cp) acc += sfeat[cp*8+q]*Woff[cp*24+j];
    soff[q][j] = acc;
  }
  if (tid < 72) {
    int q = 5+tid/24, j = tid%24;
    float acc = boff[j];
    for (int cp = 0; cp < CC; ++cp) acc += sfeat[cp*8+q]*Woff[cp*24+j];
    soff[q][j] = acc;
  }
  __syncthreads();
  const int wvid = tid >> 6;
  for (int q = 0; q < 8; ++q) {
    float px = spos[q*3+0], py = spos[q*3+1], pz = spos[q*3+2];
    float a8[8];
#pragma unroll
    for (int j = 0; j < 8; ++j) {
      float ox = px+soff[q][j*3+0], oy = py+soff[q][j*3+1], oz = pz+soff[q][j*3+2];
      float a = bil(bxz,ox,oz,es,rs)+bil(bxy,ox,oy,es,rs)+bil(byz,oy,oz,es,rs);
      a8[j] = a;
      float p = a * qk[q];
#pragma unroll
      for (int m = 1; m < 64; m <<= 1) p += __shfl_xor(p, m);
      if ((tid & 63) == 0) sred[q][wvid][j] = p;
    }
    __syncthreads();
    float attn[8], mx = -INFINITY;
#pragma unroll
    for (int j = 0; j < 8; ++j) { attn[j] = sred[q][0][j]+sred[q][1][j]; mx = fmaxf(mx, attn[j]); }
    float den = 0.f;
#pragma unroll
    for (int j = 0; j < 8; ++j) { attn[j] = __expf(attn[j]-mx); den += attn[j]; }
    float inv = 1.f/den, w = 0.f;
#pragma unroll
    for (int j = 0; j < 8; ++j) w += attn[j]*a8[j];
    swv[c*8+q] = w*inv;
  }
  __syncthreads();
  float o[8];
  {
    float bb = b2[c];
#pragma unroll
    for (int q = 0; q < 8; ++q) o[q] = bb;
    for (int cp = 0; cp < CC; ++cp) {
      float wv2 = W2[cp*CC+c];
#pragma unroll
      for (int q = 0; q < 8; ++q) o[q] += wv2 * swv[cp*8+q];
    }
  }
#pragma unroll
  for (int q = 0; q < 8; ++q)
    out[(size_t)(b*NN+n0+q)*CC+c] = o[q] + sfeat[c*8+q];
}

extern "C" void kernel_launch(void* const* d_in, const int* in_sizes, int n_in,
                              void* d_out, int out_size, void* d_ws, size_t ws_size,
                              hipStream_t stream) {
  const float* qpos = (const float*)d_in[0];
  const float* pxz  = (const float*)d_in[1];
  const float* pxy  = (const float*)d_in[2];
  const float* pyz  = (const float*)d_in[3];
  const float* Wq   = (const float*)d_in[4];
  const float* bq   = (const float*)d_in[5];
  const float* Wk   = (const float*)d_in[6];
  // d_in[7] = bk: q.bk is constant over the S axis -> cancels in softmax
  const float* Wv   = (const float*)d_in[8];
  const float* bv   = (const float*)d_in[9];
  const float* Wout = (const float*)d_in[10];
  const float* bout = (const float*)d_in[11];
  const float* Woff = (const float*)d_in[12];
  const float* boff = (const float*)d_in[13];
  float* out = (float*)d_out;

  float* w = (float*)d_ws;
  const size_t nT = (size_t)3 * BB * HW * CC;
  const size_t matFloats = 16384 + 128 + 16384 + 128 + 24 * 128;
  const size_t sidxInts = (size_t)BB * NN;
  bool tp = ws_size >= (nT + matFloats + sidxInts) * sizeof(float);

  float* wsT  = w;
  float* wsMt = tp ? (w + nT) : w;
  float* wsU  = wsMt + 16384;
  float* wsW2 = wsU + 128;
  float* wsB2 = wsW2 + 16384;
  float* wsWofft = wsB2 + 128;
  int*   wsSidx  = (int*)(wsWofft + 24 * 128);

  prep_mats<<<258, 128, 0, stream>>>(Wq, bq, Wk, Wv, bv, Wout, bout, Woff,
                                     wsMt, wsU, wsW2, wsB2, wsWofft);
  if (tp) {
    sort_queries<<<BB, 1024, 0, stream>>>(qpos, wsSidx);
    transpose_planes<<<3 * BB * (HW / 16), 128, 0, stream>>>(pxz, pxy, pyz, wsT);
    deform_attn9<<<(BB * NN) / 8, 128, 0, stream>>>(
        qpos, wsSidx, wsT, wsMt, wsU, wsW2, wsB2, wsWofft, boff, out);
  } else {
    deform_attn_fb<<<(BB * NN) / 8, 128, 0, stream>>>(
        qpos, pxz, pxy, pyz, wsMt, wsU, wsW2, wsB2, Woff, boff, out);
  }
}